// Round 8
// baseline (189.567 us; speedup 1.0000x reference)
//
#include <hip/hip_runtime.h>
#include <hip/hip_bf16.h>
#include <stdint.h>

typedef unsigned short u16;
typedef __bf16 bf16x8 __attribute__((ext_vector_type(8)));
typedef float f32x4 __attribute__((ext_vector_type(4)));
typedef float f32x16 __attribute__((ext_vector_type(16)));

__device__ __forceinline__ u16 f2bf(float f) {
    union { float f; unsigned u; } x; x.f = f;
    unsigned u = x.u;
    u += 0x7FFFu + ((u >> 16) & 1u);   // round-to-nearest-even
    return (u16)(u >> 16);
}
__device__ __forceinline__ float bf2f(u16 h) {
    union { unsigned u; float f; } x; x.u = ((unsigned)h) << 16; return x.f;
}

// async global->LDS, 16B per lane; LDS dest is wave-uniform base + lane*16.
typedef __attribute__((address_space(1))) void gvoid;
typedef __attribute__((address_space(3))) void lvoid;
__device__ __forceinline__ void gl2lds16(const void* g, void* l) {
    __builtin_amdgcn_global_load_lds((gvoid*)g, (lvoid*)l, 16, 0, 0);
}

// ---------------------------------------------------------------------------
// Merged prep: blocks [0,2048): cast x -> bf16; [2048,2816): castT Wqkv;
// [2816,3072): castT Wproj.
// ---------------------------------------------------------------------------
__global__ __launch_bounds__(256) void prep_kernel(
    const float* __restrict__ x, u16* __restrict__ xb,
    const float* __restrict__ Wqkv, u16* __restrict__ wqkvT,
    const float* __restrict__ Wproj, u16* __restrict__ wprojT)
{
    __shared__ u16 tile[64][65];
    const int blk = blockIdx.x;
    const int tid = threadIdx.x;

    if (blk < 2048) {
        const size_t i = ((size_t)blk * 256 + tid) * 8;
        float4 a = *(const float4*)(x + i);
        float4 b = *(const float4*)(x + i + 4);
        ushort4 oa, ob;
        oa.x = f2bf(a.x); oa.y = f2bf(a.y); oa.z = f2bf(a.z); oa.w = f2bf(a.w);
        ob.x = f2bf(b.x); ob.y = f2bf(b.y); ob.z = f2bf(b.z); ob.w = f2bf(b.w);
        *(ushort4*)(xb + i) = oa;
        *(ushort4*)(xb + i + 4) = ob;
        return;
    }
    const float* in; u16* out; int rows, cols, bx, by;
    if (blk < 2816) { int t = blk - 2048; in = Wqkv;  out = wqkvT;  rows = 1024; cols = 3072; bx = t % 48; by = t / 48; }
    else            { int t = blk - 2816; in = Wproj; out = wprojT; rows = 1024; cols = 1024; bx = t % 16; by = t / 16; }
#pragma unroll
    for (int i = 0; i < 16; i++) {
        int e = i * 256 + tid;
        int r = e >> 6, c = e & 63;
        tile[r][c] = f2bf(in[(size_t)(by * 64 + r) * cols + bx * 64 + c]);
    }
    __syncthreads();
#pragma unroll
    for (int i = 0; i < 16; i++) {
        int e = i * 256 + tid;
        int r = e >> 6, c = e & 63;
        out[(size_t)(bx * 64 + r) * rows + by * 64 + c] = tile[c][r];
    }
}

// ---------------------------------------------------------------------------
// QKV GEMM v6c: v6b (64m x 128n, grid 1536, natural launch bounds, T2
// swizzle) + V-epilogue writes vt with tokens PERMUTED within each 16-group
// by PERM = p(s) = 4*(s>>3) + (s&3) + 8*((s>>2)&1) -- the 32x32 MFMA A-slot
// order. attn can then read its V fragment as ONE contiguous b128 (the
// conflict-free K pattern) instead of two 4-way-conflicted b64s.
// Free here: the V pack loop already gathers per-row; only row index changes.
// ---------------------------------------------------------------------------
__global__ __launch_bounds__(256) void gemm_qkv(
    const u16* __restrict__ A, const u16* __restrict__ Bt,
    const float* __restrict__ bias,
    u16* __restrict__ q, u16* __restrict__ ko, u16* __restrict__ vt)
{
    constexpr int K = 1024;
    __shared__ __align__(16) u16 smem[64 * 64 + 128 * 64];   // 24 KB
    u16* sA = smem;           // 64 x 64
    u16* sB = smem + 4096;    // 128 x 64
    const int tid = threadIdx.x;
    const int wave = tid >> 6, lane = tid & 63;
    const int quad = lane >> 4, l16 = lane & 15;
    const int wm = (wave >> 1) * 32, wn = (wave & 1) * 64;
    const int m0 = blockIdx.y * 64, n0 = blockIdx.x * 128;
    const int srow = lane >> 3;                    // 0..7
    const int scolz = ((lane & 7) ^ srow) * 8;     // swizzled SOURCE col

    f32x4 acc[2][4];
#pragma unroll
    for (int i = 0; i < 2; i++)
#pragma unroll
        for (int j = 0; j < 4; j++)
#pragma unroll
            for (int r = 0; r < 4; r++) acc[i][j][r] = 0.f;

    for (int kt = 0; kt < K; kt += 64) {
        __syncthreads();
#pragma unroll
        for (int t = 0; t < 2; t++) {
            int rb = wave * 16 + t * 8;
            gl2lds16(A + (size_t)(m0 + rb + srow) * K + kt + scolz, &sA[rb * 64]);
        }
#pragma unroll
        for (int t = 0; t < 4; t++) {
            int rb = wave * 32 + t * 8;
            gl2lds16(Bt + (size_t)(n0 + rb + srow) * K + kt + scolz, &sB[rb * 64]);
        }
        __syncthreads();
#pragma unroll
        for (int kk = 0; kk < 64; kk += 32) {
            bf16x8 af[2], bfr[4];
            int sl = (((kk >> 3) + quad) ^ (l16 & 7)) * 8;   // swizzled slot
#pragma unroll
            for (int t = 0; t < 2; t++)
                af[t] = *(const bf16x8*)&sA[(wm + t * 16 + l16) * 64 + sl];
#pragma unroll
            for (int t = 0; t < 4; t++)
                bfr[t] = *(const bf16x8*)&sB[(wn + t * 16 + l16) * 64 + sl];
#pragma unroll
            for (int i = 0; i < 2; i++)
#pragma unroll
                for (int j = 0; j < 4; j++)
                    acc[i][j] = __builtin_amdgcn_mfma_f32_16x16x32_bf16(
                        af[i], bfr[j], acc[i][j], 0, 0, 0);
        }
    }

    const float QSCALE = 0.18033688011112042f;  // 0.125 * log2(e)
    const float sc = (n0 < 1024) ? QSCALE : 1.0f;
    __syncthreads();
#pragma unroll
    for (int i = 0; i < 2; i++) {
#pragma unroll
        for (int j = 0; j < 4; j++) {
            float bv = bias[n0 + wn + j * 16 + l16];
#pragma unroll
            for (int r = 0; r < 4; r++) {
                float v = (acc[i][j][r] + bv) * sc;
                smem[(wm + i * 16 + quad * 4 + r) * 132 + wn + j * 16 + l16] = f2bf(v);
            }
        }
    }
    __syncthreads();

    if (n0 < 2048) {
        u16* dst = (n0 < 1024) ? q : ko;
#pragma unroll
        for (int it = 0; it < 4; it++) {
            int c = it * 256 + tid;
            int m_l = c >> 4;                 // 0..63
            int n8 = (c & 15) * 8;
            uint4 w = *(const uint4*)&smem[m_l * 132 + n8];
            int n = n0 + n8;
            int h = (n & 1023) >> 6, d = n & 63;
            int m = m0 + m_l;
            int b = m >> 11, t = m & 2047;
            *(uint4*)(dst + ((size_t)(b * 16 + h) * 2048 + t) * 64 + d) = w;
        }
    } else {
        // V epilogue: vt[(bh*64+d)*2048 + g*16 + s] = V[token g*16+PERM[s]][d]
        constexpr int PERM[16] = {0,1,2,3, 8,9,10,11, 4,5,6,7, 12,13,14,15};
        int nv = n0 - 2048;
        int n_l = tid & 127, mh = tid >> 7;   // mh 0..1, 32 rows each
        int hh = (nv >> 6) + (n_l >> 6);
        int d = n_l & 63;
        int bb = m0 >> 11, t0 = m0 & 2047;
        u16* vrow = vt + ((size_t)(bb * 16 + hh) * 64 + d) * 2048 + t0 + mh * 32;
#pragma unroll
        for (int it = 0; it < 4; it++) {
            int base = mh * 32 + it * 8;      // vt position base (mult of 8)
            union { u16 s[8]; uint4 w; } pk;
#pragma unroll
            for (int i = 0; i < 8; i++) {
                int pos = base + i;
                int row = (pos & ~15) | PERM[pos & 15];
                pk.s[i] = smem[row * 132 + n_l];
            }
            *(uint4*)(vrow + it * 8) = pk.w;
        }
    }
}

// ---------------------------------------------------------------------------
// Flash attention v13: v11 + single-b128 V fragment reads (vt pre-permuted
// by gemm_qkv so MFMA slot order == memory order). Kills the 4096/block
// 4-way b64 conflicts (the entire 4.19M residue). Pairing: P slot (hi,j)
// holds krow base+p(hi*8+j); permuted vt slot (hi,j) holds token
// base+p(hi*8+j) -- identical, and p is a bijection within each 16-group.
// ---------------------------------------------------------------------------
__global__ __launch_bounds__(256, 4) void attn_kernel(
    const u16* __restrict__ q, const u16* __restrict__ ko,
    const u16* __restrict__ vt,
    u16* __restrict__ op0, u16* __restrict__ op1,
    float* __restrict__ lp0, float* __restrict__ lp1)
{
    __shared__ __align__(16) u16 sK[2][64 * 72];   // [n][d], pitch 72
    __shared__ __align__(16) u16 sV[2][64 * 72];   // [d][n], pitch 72

    const int tid = threadIdx.x;
    const int wave = tid >> 6, lane = tid & 63;
    const int l31 = lane & 31, hi = lane >> 5;

    const int lid = blockIdx.x;
    const int xcd = lid & 7, idx = lid >> 3;     // idx 0..127
    const int h = xcd * 2 + (idx & 1);
    const int b = (idx >> 1) & 1;
    const int q0 = ((idx >> 2) & 15) * 128;
    const int khalf = idx >> 6;                  // 0 or 1
    const int kbase = khalf * 1024;
    const size_t bh = (size_t)(b * 16 + h);

    const u16* qp  = q  + bh * 2048 * 64;
    const u16* kp  = ko + bh * 2048 * 64;
    const u16* vtp = vt + bh * 64 * 2048;

    // Q fragments straight from global: B-operand of 32x32x16.
    bf16x8 qf[4];
    {
        const u16* qrow = qp + (size_t)(q0 + wave * 32 + l31) * 64 + hi * 8;
#pragma unroll
        for (int d = 0; d < 4; d++)
            qf[d] = *(const bf16x8*)(qrow + d * 16);
    }

    const int sr0 = tid >> 3;          // 0..31
    const int sc0 = (tid & 7) * 8;
    const int sr1 = sr0 + 32;

    // prefetch tile 0 K/V of this half
    uint4 pk0 = *(const uint4*)(kp + (size_t)(kbase + sr0) * 64 + sc0);
    uint4 pk1 = *(const uint4*)(kp + (size_t)(kbase + sr1) * 64 + sc0);
    uint4 pv0 = *(const uint4*)(vtp + (size_t)sr0 * 2048 + kbase + sc0);
    uint4 pv1 = *(const uint4*)(vtp + (size_t)sr1 * 2048 + kbase + sc0);

    f32x16 accO[2];
#pragma unroll
    for (int d = 0; d < 2; d++)
#pragma unroll
        for (int r = 0; r < 16; r++) accO[d][r] = 0.f;
    float ls[4] = {0.f, 0.f, 0.f, 0.f};

    for (int t = 0; t < 16; ++t) {
        const int cur = t & 1;
        u16* sKc = &sK[cur][0];
        u16* sVc = &sV[cur][0];
        *(uint4*)&sKc[sr0 * 72 + sc0] = pk0;
        *(uint4*)&sKc[sr1 * 72 + sc0] = pk1;
        *(uint4*)&sVc[sr0 * 72 + sc0] = pv0;
        *(uint4*)&sVc[sr1 * 72 + sc0] = pv1;
        if (t < 15) {
            int nt = kbase + (t + 1) * 64;
            pk0 = *(const uint4*)(kp + (size_t)(nt + sr0) * 64 + sc0);
            pk1 = *(const uint4*)(kp + (size_t)(nt + sr1) * 64 + sc0);
            pv0 = *(const uint4*)(vtp + (size_t)sr0 * 2048 + nt + sc0);
            pv1 = *(const uint4*)(vtp + (size_t)sr1 * 2048 + nt + sc0);
        }
        __syncthreads();   // sole barrier: tile t staged; buffer cur^1 free

#pragma unroll
        for (int rb = 0; rb < 2; rb++) {
            // S^T block: D = mfma(A=K, B=Q), lane holds
            // S^T[krow = (r&3)+8*(r>>2)+4*hi][q = l31] (rows rb*32..+31)
            f32x16 S;
#pragma unroll
            for (int r = 0; r < 16; r++) S[r] = 0.f;
            const u16* krd = &sKc[(rb * 32 + l31) * 72 + hi * 8];
#pragma unroll
            for (int d = 0; d < 4; d++) {
                bf16x8 kf = *(const bf16x8*)(krd + d * 16);
                S = __builtin_amdgcn_mfma_f32_32x32x16_bf16(kf, qf[d], S, 0, 0, 0);
            }
            union { float f; unsigned u; } e[16];
#pragma unroll
            for (int r = 0; r < 16; r++) {
                e[r].f = __builtin_amdgcn_exp2f(S[r]);
                ls[r & 3] += e[r].f;
            }
            // O += P @ V. pa slot (hi,j) <- P[krow base+p(hi*8+j)];
            // vt pre-permuted so one b128 at hi*8 delivers the same tokens.
#pragma unroll
            for (int ks2 = 0; ks2 < 2; ks2++) {
                union { unsigned u[4]; bf16x8 v; } pa;
#pragma unroll
                for (int s = 0; s < 4; s++) {
                    unsigned r0 = e[ks2 * 8 + 2 * s].u + 0x8000u;      // RN
                    unsigned r1 = e[ks2 * 8 + 2 * s + 1].u + 0x8000u;  // RN
                    pa.u[s] = (r1 & 0xFFFF0000u) | (r0 >> 16);
                }
                const int nb = rb * 32 + ks2 * 16 + hi * 8;
#pragma unroll
                for (int db = 0; db < 2; db++) {
                    bf16x8 vf = *(const bf16x8*)&sVc[(db * 32 + l31) * 72 + nb];
                    accO[db] = __builtin_amdgcn_mfma_f32_32x32x16_bf16(pa.v, vf, accO[db], 0, 0, 0);
                }
            }
        }
    }

    // epilogue: write unnormalized O (bf16) + l (fp32) for this half
    u16* op = khalf ? op1 : op0;
    float* lp = khalf ? lp1 : lp0;

    float lsum = (ls[0] + ls[1]) + (ls[2] + ls[3]);
    float ltot = lsum + __shfl_xor(lsum, 32, 64);
    int qq0 = q0 + wave * 32;
    if (hi == 0) lp[bh * 2048 + qq0 + l31] = ltot;

#pragma unroll
    for (int db = 0; db < 2; db++)
#pragma unroll
        for (int r = 0; r < 16; r++) {
            int tq = qq0 + (r & 3) + 8 * (r >> 2) + 4 * hi;
            size_t row = (size_t)b * 2048 + tq;
            op[row * 1024 + h * 64 + db * 32 + l31] = f2bf(accO[db][r]);
        }
}

// ---------------------------------------------------------------------------
// Combine: ob = (O0 + O1) / (l0 + l1); ob aliases op0 (same-element RMW safe).
// ---------------------------------------------------------------------------
__global__ __launch_bounds__(256) void combine_kernel(
    const u16* __restrict__ op0, const u16* __restrict__ op1,
    const float* __restrict__ lp0, const float* __restrict__ lp1,
    u16* __restrict__ ob)
{
    const size_t i = ((size_t)blockIdx.x * 256 + threadIdx.x) * 8;
    int m = (int)(i >> 10), e = (int)(i & 1023);
    int b = m >> 11, t = m & 2047, h = e >> 6;
    float inv = 1.f / (lp0[(size_t)(b * 16 + h) * 2048 + t] +
                       lp1[(size_t)(b * 16 + h) * 2048 + t]);
    union { uint4 w; u16 s[8]; } a, c, o;
    a.w = *(const uint4*)(op0 + i);
    c.w = *(const uint4*)(op1 + i);
#pragma unroll
    for (int k = 0; k < 8; k++)
        o.s[k] = f2bf((bf2f(a.s[k]) + bf2f(c.s[k])) * inv);
    *(uint4*)(ob + i) = o.w;
}

// ---------------------------------------------------------------------------
// Proj GEMM v5 (frozen): T2 XOR-swizzle, 64m x 128n tiles, grid 512.
// ---------------------------------------------------------------------------
__global__ __launch_bounds__(256) void gemm_proj(
    const u16* __restrict__ A, const u16* __restrict__ Bt,
    const float* __restrict__ bias, float* __restrict__ out)
{
    constexpr int K = 1024;
    __shared__ __align__(16) u16 sA[64 * 64];
    __shared__ __align__(16) u16 sB[128 * 64];
    const int tid = threadIdx.x;
    const int wave = tid >> 6, lane = tid & 63;
    const int quad = lane >> 4, l16 = lane & 15;
    const int wm = (wave & 1) * 32, wn = (wave >> 1) * 64;

    const int lid = blockIdx.x;
    const int xcd = lid & 7, idx = lid >> 3;   // idx 0..63
    const int m0 = (xcd * 8 + (idx & 7)) * 64;
    const int n0 = (idx >> 3) * 128;

    const int srow = lane >> 3;
    const int scolz = ((lane & 7) ^ srow) * 8;     // swizzled SOURCE col

    f32x4 acc[2][4];
#pragma unroll
    for (int i = 0; i < 2; i++)
#pragma unroll
        for (int j = 0; j < 4; j++)
#pragma unroll
            for (int r = 0; r < 4; r++) acc[i][j][r] = 0.f;

    for (int kt = 0; kt < K; kt += 64) {
        __syncthreads();
#pragma unroll
        for (int t = 0; t < 2; t++) {
            int rb = wave * 16 + t * 8;
            gl2lds16(A + (size_t)(m0 + rb + srow) * K + kt + scolz, &sA[rb * 64]);
        }
#pragma unroll
        for (int t = 0; t < 4; t++) {
            int rb = wave * 32 + t * 8;
            gl2lds16(Bt + (size_t)(n0 + rb + srow) * K + kt + scolz, &sB[rb * 64]);
        }
        __syncthreads();
#pragma unroll
        for (int kk = 0; kk < 64; kk += 32) {
            bf16x8 af[2], bfr[4];
            int sl = (((kk >> 3) + quad) ^ (l16 & 7)) * 8;   // swizzled slot
#pragma unroll
            for (int t = 0; t < 2; t++)
                af[t] = *(const bf16x8*)&sA[(wm + t * 16 + l16) * 64 + sl];
#pragma unroll
            for (int t = 0; t < 4; t++)
                bfr[t] = *(const bf16x8*)&sB[(wn + t * 16 + l16) * 64 + sl];
#pragma unroll
            for (int i = 0; i < 2; i++)
#pragma unroll
                for (int j = 0; j < 4; j++)
                    acc[i][j] = __builtin_amdgcn_mfma_f32_16x16x32_bf16(
                        af[i], bfr[j], acc[i][j], 0, 0, 0);
        }
    }

#pragma unroll
    for (int i = 0; i < 2; i++) {
#pragma unroll
        for (int j = 0; j < 4; j++) {
            int n = n0 + wn + j * 16 + l16;
            float bv = bias[n];
#pragma unroll
            for (int r = 0; r < 4; r++) {
                int m = m0 + wm + i * 16 + quad * 4 + r;
                out[(size_t)m * 1024 + n] = acc[i][j][r] + bv;
            }
        }
    }
}

// ---------------------------------------------------------------------------
extern "C" void kernel_launch(void* const* d_in, const int* in_sizes, int n_in,
                              void* d_out, int out_size, void* d_ws, size_t ws_size,
                              hipStream_t stream) {
    const float* x     = (const float*)d_in[0];
    const float* Wqkv  = (const float*)d_in[1];
    const float* bqkv  = (const float*)d_in[2];
    const float* Wproj = (const float*)d_in[3];
    const float* bproj = (const float*)d_in[4];
    float* out = (float*)d_out;
    char* ws = (char*)d_ws;

    u16* wqkvT  = (u16*)(ws);              // 6291456 B (dead after gemm_qkv)
    u16* wprojT = (u16*)(ws +  6291456);   // 2097152 B (live until gemm_proj)
    u16* xb     = (u16*)(ws +  8388608);   // 8388608 B (dead after gemm_qkv)
    u16* qb     = (u16*)(ws + 16777216);   // [B,H,N,D]
    u16* kb     = (u16*)(ws + 25165824);   // [B,H,N,D]
    u16* vtb    = (u16*)(ws + 33554432);   // [B,H,D,N] (token-permuted /16)
    u16* ob     = (u16*)(ws + 41943040);   // [B,N,E]  (= op0, combined in place)

    // partial buffers reuse dead slots during attention:
    u16*   op0 = ob;                       // half-0 unnormalized O (bf16)
    u16*   op1 = xb;                       // half-1 unnormalized O (bf16)
    float* lp0 = (float*)wqkvT;            // 65536 floats = 256 KB
    float* lp1 = (float*)(ws + 262144);    // next 256 KB (still in wqkvT slot)

    prep_kernel<<<dim3(3072), 256, 0, stream>>>(x, xb, Wqkv, wqkvT, Wproj, wprojT);
    gemm_qkv<<<dim3(24, 64), 256, 0, stream>>>(xb, wqkvT, bqkv, qb, kb, vtb);
    attn_kernel<<<dim3(1024), 256, 0, stream>>>(qb, kb, vtb, op0, op1, lp0, lp1);
    combine_kernel<<<dim3(2048), 256, 0, stream>>>(op0, op1, lp0, lp1, ob);
    gemm_proj<<<dim3(512), 256, 0, stream>>>(ob, wprojT, bproj, out);
}

// Round 9
// 178.846 us; speedup vs baseline: 1.0599x; 1.0599x over previous
//
#include <hip/hip_runtime.h>
#include <hip/hip_bf16.h>
#include <stdint.h>

typedef unsigned short u16;
typedef __bf16 bf16x8 __attribute__((ext_vector_type(8)));
typedef float f32x4 __attribute__((ext_vector_type(4)));
typedef float f32x16 __attribute__((ext_vector_type(16)));

__device__ __forceinline__ u16 f2bf(float f) {
    union { float f; unsigned u; } x; x.f = f;
    unsigned u = x.u;
    u += 0x7FFFu + ((u >> 16) & 1u);   // round-to-nearest-even
    return (u16)(u >> 16);
}
__device__ __forceinline__ float bf2f(u16 h) {
    union { unsigned u; float f; } x; x.u = ((unsigned)h) << 16; return x.f;
}

// async global->LDS, 16B per lane; LDS dest is wave-uniform base + lane*16.
typedef __attribute__((address_space(1))) void gvoid;
typedef __attribute__((address_space(3))) void lvoid;
__device__ __forceinline__ void gl2lds16(const void* g, void* l) {
    __builtin_amdgcn_global_load_lds((gvoid*)g, (lvoid*)l, 16, 0, 0);
}

// ---------------------------------------------------------------------------
// Merged prep: blocks [0,2048): cast x -> bf16; [2048,2816): castT Wqkv;
// [2816,3072): castT Wproj.
// ---------------------------------------------------------------------------
__global__ __launch_bounds__(256) void prep_kernel(
    const float* __restrict__ x, u16* __restrict__ xb,
    const float* __restrict__ Wqkv, u16* __restrict__ wqkvT,
    const float* __restrict__ Wproj, u16* __restrict__ wprojT)
{
    __shared__ u16 tile[64][65];
    const int blk = blockIdx.x;
    const int tid = threadIdx.x;

    if (blk < 2048) {
        const size_t i = ((size_t)blk * 256 + tid) * 8;
        float4 a = *(const float4*)(x + i);
        float4 b = *(const float4*)(x + i + 4);
        ushort4 oa, ob;
        oa.x = f2bf(a.x); oa.y = f2bf(a.y); oa.z = f2bf(a.z); oa.w = f2bf(a.w);
        ob.x = f2bf(b.x); ob.y = f2bf(b.y); ob.z = f2bf(b.z); ob.w = f2bf(b.w);
        *(ushort4*)(xb + i) = oa;
        *(ushort4*)(xb + i + 4) = ob;
        return;
    }
    const float* in; u16* out; int rows, cols, bx, by;
    if (blk < 2816) { int t = blk - 2048; in = Wqkv;  out = wqkvT;  rows = 1024; cols = 3072; bx = t % 48; by = t / 48; }
    else            { int t = blk - 2816; in = Wproj; out = wprojT; rows = 1024; cols = 1024; bx = t % 16; by = t / 16; }
#pragma unroll
    for (int i = 0; i < 16; i++) {
        int e = i * 256 + tid;
        int r = e >> 6, c = e & 63;
        tile[r][c] = f2bf(in[(size_t)(by * 64 + r) * cols + bx * 64 + c]);
    }
    __syncthreads();
#pragma unroll
    for (int i = 0; i < 16; i++) {
        int e = i * 256 + tid;
        int r = e >> 6, c = e & 63;
        out[(size_t)(bx * 64 + r) * rows + by * 64 + c] = tile[c][r];
    }
}

// ---------------------------------------------------------------------------
// QKV GEMM v6c (frozen): 64m x 128n, grid 1536, T2 swizzle, V-epilogue
// token-permuted per 16-group (PERM = 32x32 MFMA A-slot order).
// ---------------------------------------------------------------------------
__global__ __launch_bounds__(256) void gemm_qkv(
    const u16* __restrict__ A, const u16* __restrict__ Bt,
    const float* __restrict__ bias,
    u16* __restrict__ q, u16* __restrict__ ko, u16* __restrict__ vt)
{
    constexpr int K = 1024;
    __shared__ __align__(16) u16 smem[64 * 64 + 128 * 64];   // 24 KB
    u16* sA = smem;           // 64 x 64
    u16* sB = smem + 4096;    // 128 x 64
    const int tid = threadIdx.x;
    const int wave = tid >> 6, lane = tid & 63;
    const int quad = lane >> 4, l16 = lane & 15;
    const int wm = (wave >> 1) * 32, wn = (wave & 1) * 64;
    const int m0 = blockIdx.y * 64, n0 = blockIdx.x * 128;
    const int srow = lane >> 3;                    // 0..7
    const int scolz = ((lane & 7) ^ srow) * 8;     // swizzled SOURCE col

    f32x4 acc[2][4];
#pragma unroll
    for (int i = 0; i < 2; i++)
#pragma unroll
        for (int j = 0; j < 4; j++)
#pragma unroll
            for (int r = 0; r < 4; r++) acc[i][j][r] = 0.f;

    for (int kt = 0; kt < K; kt += 64) {
        __syncthreads();
#pragma unroll
        for (int t = 0; t < 2; t++) {
            int rb = wave * 16 + t * 8;
            gl2lds16(A + (size_t)(m0 + rb + srow) * K + kt + scolz, &sA[rb * 64]);
        }
#pragma unroll
        for (int t = 0; t < 4; t++) {
            int rb = wave * 32 + t * 8;
            gl2lds16(Bt + (size_t)(n0 + rb + srow) * K + kt + scolz, &sB[rb * 64]);
        }
        __syncthreads();
#pragma unroll
        for (int kk = 0; kk < 64; kk += 32) {
            bf16x8 af[2], bfr[4];
            int sl = (((kk >> 3) + quad) ^ (l16 & 7)) * 8;   // swizzled slot
#pragma unroll
            for (int t = 0; t < 2; t++)
                af[t] = *(const bf16x8*)&sA[(wm + t * 16 + l16) * 64 + sl];
#pragma unroll
            for (int t = 0; t < 4; t++)
                bfr[t] = *(const bf16x8*)&sB[(wn + t * 16 + l16) * 64 + sl];
#pragma unroll
            for (int i = 0; i < 2; i++)
#pragma unroll
                for (int j = 0; j < 4; j++)
                    acc[i][j] = __builtin_amdgcn_mfma_f32_16x16x32_bf16(
                        af[i], bfr[j], acc[i][j], 0, 0, 0);
        }
    }

    const float QSCALE = 0.18033688011112042f;  // 0.125 * log2(e)
    const float sc = (n0 < 1024) ? QSCALE : 1.0f;
    __syncthreads();
#pragma unroll
    for (int i = 0; i < 2; i++) {
#pragma unroll
        for (int j = 0; j < 4; j++) {
            float bv = bias[n0 + wn + j * 16 + l16];
#pragma unroll
            for (int r = 0; r < 4; r++) {
                float v = (acc[i][j][r] + bv) * sc;
                smem[(wm + i * 16 + quad * 4 + r) * 132 + wn + j * 16 + l16] = f2bf(v);
            }
        }
    }
    __syncthreads();

    if (n0 < 2048) {
        u16* dst = (n0 < 1024) ? q : ko;
#pragma unroll
        for (int it = 0; it < 4; it++) {
            int c = it * 256 + tid;
            int m_l = c >> 4;                 // 0..63
            int n8 = (c & 15) * 8;
            uint4 w = *(const uint4*)&smem[m_l * 132 + n8];
            int n = n0 + n8;
            int h = (n & 1023) >> 6, d = n & 63;
            int m = m0 + m_l;
            int b = m >> 11, t = m & 2047;
            *(uint4*)(dst + ((size_t)(b * 16 + h) * 2048 + t) * 64 + d) = w;
        }
    } else {
        // V epilogue: vt[(bh*64+d)*2048 + g*16 + s] = V[token g*16+PERM[s]][d]
        constexpr int PERM[16] = {0,1,2,3, 8,9,10,11, 4,5,6,7, 12,13,14,15};
        int nv = n0 - 2048;
        int n_l = tid & 127, mh = tid >> 7;   // mh 0..1, 32 rows each
        int hh = (nv >> 6) + (n_l >> 6);
        int d = n_l & 63;
        int bb = m0 >> 11, t0 = m0 & 2047;
        u16* vrow = vt + ((size_t)(bb * 16 + hh) * 64 + d) * 2048 + t0 + mh * 32;
#pragma unroll
        for (int it = 0; it < 4; it++) {
            int base = mh * 32 + it * 8;      // vt position base (mult of 8)
            union { u16 s[8]; uint4 w; } pk;
#pragma unroll
            for (int i = 0; i < 8; i++) {
                int pos = base + i;
                int row = (pos & ~15) | PERM[pos & 15];
                pk.s[i] = smem[row * 132 + n_l];
            }
            *(uint4*)(vrow + it * 8) = pk.w;
        }
    }
}

// ---------------------------------------------------------------------------
// Flash attention v14: in-block K-split. 512 threads = 8 waves = 4 q-waves x
// 2 k-halves; each wave runs the proven v13 per-wave program on its half
// (own sK/sV pair, same single-barrier double-buffer schedule -- barriers
// now couple both halves, same count). Epilogue: khalf1 waves post accO
// (f32) + l to LDS; khalf0 waves add in FULL f32, normalize by (l0+l1),
// write final ob directly. Eliminates combine kernel, partial-O round-trip
// (16.9 MB write + 33 MB read), and one launch. LDS 73.7 KB -> 2 blocks/CU
// = 16 waves/CU (same as v13's 4x4). Grid 512.
// ---------------------------------------------------------------------------
__global__ __launch_bounds__(512) void attn_kernel(
    const u16* __restrict__ q, const u16* __restrict__ ko,
    const u16* __restrict__ vt, u16* __restrict__ ob)
{
    __shared__ __align__(16) u16 sK[2][2][64 * 72];   // [khalf][buf][n][d]
    __shared__ __align__(16) u16 sV[2][2][64 * 72];   // [khalf][buf][d][n]

    const int tid = threadIdx.x;
    const int wave = tid >> 6, lane = tid & 63;
    const int l31 = lane & 31, hi = lane >> 5;
    const int khalf = wave >> 2, qw = wave & 3;
    const int kbase = khalf * 1024;

    const int lid = blockIdx.x;
    const int xcd = lid & 7, idx = lid >> 3;     // idx 0..63
    const int h = xcd * 2 + (idx & 1);
    const int b = (idx >> 1) & 1;
    const int q0 = ((idx >> 2) & 15) * 128;
    const size_t bh = (size_t)(b * 16 + h);

    const u16* qp  = q  + bh * 2048 * 64;
    const u16* kp  = ko + bh * 2048 * 64;
    const u16* vtp = vt + bh * 64 * 2048;

    // Q fragments straight from global: B-operand of 32x32x16.
    bf16x8 qf[4];
    {
        const u16* qrow = qp + (size_t)(q0 + qw * 32 + l31) * 64 + hi * 8;
#pragma unroll
        for (int d = 0; d < 4; d++)
            qf[d] = *(const bf16x8*)(qrow + d * 16);
    }

    // staging role: 256 threads per khalf group
    const int gt = tid & 255;
    const int sr0 = gt >> 3;           // 0..31
    const int sc0 = (gt & 7) * 8;
    const int sr1 = sr0 + 32;

    // prefetch tile 0 of this half
    uint4 pk0 = *(const uint4*)(kp + (size_t)(kbase + sr0) * 64 + sc0);
    uint4 pk1 = *(const uint4*)(kp + (size_t)(kbase + sr1) * 64 + sc0);
    uint4 pv0 = *(const uint4*)(vtp + (size_t)sr0 * 2048 + kbase + sc0);
    uint4 pv1 = *(const uint4*)(vtp + (size_t)sr1 * 2048 + kbase + sc0);

    f32x16 accO[2];
#pragma unroll
    for (int d = 0; d < 2; d++)
#pragma unroll
        for (int r = 0; r < 16; r++) accO[d][r] = 0.f;
    float ls[4] = {0.f, 0.f, 0.f, 0.f};

    for (int t = 0; t < 16; ++t) {
        const int cur = t & 1;
        u16* sKc = &sK[khalf][cur][0];
        u16* sVc = &sV[khalf][cur][0];
        *(uint4*)&sKc[sr0 * 72 + sc0] = pk0;
        *(uint4*)&sKc[sr1 * 72 + sc0] = pk1;
        *(uint4*)&sVc[sr0 * 72 + sc0] = pv0;
        *(uint4*)&sVc[sr1 * 72 + sc0] = pv1;
        if (t < 15) {
            int nt = kbase + (t + 1) * 64;
            pk0 = *(const uint4*)(kp + (size_t)(nt + sr0) * 64 + sc0);
            pk1 = *(const uint4*)(kp + (size_t)(nt + sr1) * 64 + sc0);
            pv0 = *(const uint4*)(vtp + (size_t)sr0 * 2048 + nt + sc0);
            pv1 = *(const uint4*)(vtp + (size_t)sr1 * 2048 + nt + sc0);
        }
        __syncthreads();   // sole barrier: tile t staged (both halves)

#pragma unroll
        for (int rb = 0; rb < 2; rb++) {
            // S^T = mfma(A=K, B=Q): lane holds S^T[krow=(r&3)+8*(r>>2)+4*hi][q=l31]
            f32x16 S;
#pragma unroll
            for (int r = 0; r < 16; r++) S[r] = 0.f;
            const u16* krd = &sKc[(rb * 32 + l31) * 72 + hi * 8];
#pragma unroll
            for (int d = 0; d < 4; d++) {
                bf16x8 kf = *(const bf16x8*)(krd + d * 16);
                S = __builtin_amdgcn_mfma_f32_32x32x16_bf16(kf, qf[d], S, 0, 0, 0);
            }
            union { float f; unsigned u; } e[16];
#pragma unroll
            for (int r = 0; r < 16; r++) {
                e[r].f = __builtin_amdgcn_exp2f(S[r]);
                ls[r & 3] += e[r].f;
            }
            // O += P @ V (vt pre-permuted: one b128 per fragment, conflict-free)
#pragma unroll
            for (int ks2 = 0; ks2 < 2; ks2++) {
                union { unsigned u[4]; bf16x8 v; } pa;
#pragma unroll
                for (int s = 0; s < 4; s++) {
                    unsigned r0 = e[ks2 * 8 + 2 * s].u + 0x8000u;      // RN
                    unsigned r1 = e[ks2 * 8 + 2 * s + 1].u + 0x8000u;  // RN
                    pa.u[s] = (r1 & 0xFFFF0000u) | (r0 >> 16);
                }
                const int nb = rb * 32 + ks2 * 16 + hi * 8;
#pragma unroll
                for (int db = 0; db < 2; db++) {
                    bf16x8 vf = *(const bf16x8*)&sVc[(db * 32 + l31) * 72 + nb];
                    accO[db] = __builtin_amdgcn_mfma_f32_32x32x16_bf16(pa.v, vf, accO[db], 0, 0, 0);
                }
            }
        }
    }

    // ---- in-block combine ----
    float lsum = (ls[0] + ls[1]) + (ls[2] + ls[3]);
    float ltot = lsum + __shfl_xor(lsum, 32, 64);

    float* xO = (float*)&sK[0][0][0];   // 32 KB (fits in sK's 36.9 KB)
    float* xL = (float*)&sV[0][0][0];   // 2 x 128 floats

    __syncthreads();                    // all tile reads done; LDS reusable
    if (hi == 0) xL[khalf * 128 + qw * 32 + l31] = ltot;
    if (khalf == 1) {
#pragma unroll
        for (int db = 0; db < 2; db++)
#pragma unroll
            for (int r = 0; r < 16; r++) {
                int rloc = (r & 3) + 8 * (r >> 2) + 4 * hi;
                xO[(qw * 32 + rloc) * 64 + db * 32 + l31] = accO[db][r];
            }
    }
    __syncthreads();
    if (khalf == 0) {
#pragma unroll
        for (int db = 0; db < 2; db++)
#pragma unroll
            for (int r = 0; r < 16; r++) {
                int rloc = (r & 3) + 8 * (r >> 2) + 4 * hi;
                float inv = 1.f / (xL[qw * 32 + rloc] + xL[128 + qw * 32 + rloc]);
                float v = (accO[db][r] + xO[(qw * 32 + rloc) * 64 + db * 32 + l31]) * inv;
                int tq = q0 + qw * 32 + rloc;
                ob[((size_t)b * 2048 + tq) * 1024 + h * 64 + db * 32 + l31] = f2bf(v);
            }
    }
}

// ---------------------------------------------------------------------------
// Proj GEMM v6: 32m x 128n tiles, grid 1024 = 4 blocks/CU (was 512 = 2/CU,
// the last stall-bound 2/CU kernel). acc 16 regs, LDS 20 KB, natural launch
// bounds (round-6 lesson: never force min-waves). XCD m-super-tile: per-XCD
// A-slice 1 MB + B 2 MB, L2-resident. Same T2 swizzle.
// ---------------------------------------------------------------------------
__global__ __launch_bounds__(256) void gemm_proj(
    const u16* __restrict__ A, const u16* __restrict__ Bt,
    const float* __restrict__ bias, float* __restrict__ out)
{
    constexpr int K = 1024;
    __shared__ __align__(16) u16 sA[32 * 64];    // 4 KB
    __shared__ __align__(16) u16 sB[128 * 64];   // 16 KB
    const int tid = threadIdx.x;
    const int wave = tid >> 6, lane = tid & 63;
    const int quad = lane >> 4, l16 = lane & 15;
    const int wn = wave * 32;

    const int lid = blockIdx.x;
    const int xcd = lid & 7, idx = lid >> 3;   // idx 0..127
    const int m0 = (xcd * 16 + (idx & 15)) * 32;
    const int n0 = (idx >> 4) * 128;

    const int srow = lane >> 3;
    const int scolz = ((lane & 7) ^ srow) * 8;     // swizzled SOURCE col

    f32x4 acc[2][2];
#pragma unroll
    for (int i = 0; i < 2; i++)
#pragma unroll
        for (int j = 0; j < 2; j++)
#pragma unroll
            for (int r = 0; r < 4; r++) acc[i][j][r] = 0.f;

    for (int kt = 0; kt < K; kt += 64) {
        __syncthreads();
        {
            int rb = wave * 8;
            gl2lds16(A + (size_t)(m0 + rb + srow) * K + kt + scolz, &sA[rb * 64]);
        }
#pragma unroll
        for (int t = 0; t < 4; t++) {
            int rb = wave * 32 + t * 8;
            gl2lds16(Bt + (size_t)(n0 + rb + srow) * K + kt + scolz, &sB[rb * 64]);
        }
        __syncthreads();
#pragma unroll
        for (int kk = 0; kk < 64; kk += 32) {
            bf16x8 af[2], bfr[2];
            int sl = (((kk >> 3) + quad) ^ (l16 & 7)) * 8;   // swizzled slot
#pragma unroll
            for (int t = 0; t < 2; t++)
                af[t] = *(const bf16x8*)&sA[(t * 16 + l16) * 64 + sl];
#pragma unroll
            for (int t = 0; t < 2; t++)
                bfr[t] = *(const bf16x8*)&sB[(wn + t * 16 + l16) * 64 + sl];
#pragma unroll
            for (int i = 0; i < 2; i++)
#pragma unroll
                for (int j = 0; j < 2; j++)
                    acc[i][j] = __builtin_amdgcn_mfma_f32_16x16x32_bf16(
                        af[i], bfr[j], acc[i][j], 0, 0, 0);
        }
    }

#pragma unroll
    for (int i = 0; i < 2; i++) {
#pragma unroll
        for (int j = 0; j < 2; j++) {
            int n = n0 + wn + j * 16 + l16;
            float bv = bias[n];
#pragma unroll
            for (int r = 0; r < 4; r++) {
                int m = m0 + i * 16 + quad * 4 + r;
                out[(size_t)m * 1024 + n] = acc[i][j][r] + bv;
            }
        }
    }
}

// ---------------------------------------------------------------------------
extern "C" void kernel_launch(void* const* d_in, const int* in_sizes, int n_in,
                              void* d_out, int out_size, void* d_ws, size_t ws_size,
                              hipStream_t stream) {
    const float* x     = (const float*)d_in[0];
    const float* Wqkv  = (const float*)d_in[1];
    const float* bqkv  = (const float*)d_in[2];
    const float* Wproj = (const float*)d_in[3];
    const float* bproj = (const float*)d_in[4];
    float* out = (float*)d_out;
    char* ws = (char*)d_ws;

    u16* wqkvT  = (u16*)(ws);              // 6291456 B (dead after gemm_qkv)
    u16* wprojT = (u16*)(ws +  6291456);   // 2097152 B (live until gemm_proj)
    u16* xb     = (u16*)(ws +  8388608);   // 8388608 B (dead after gemm_qkv)
    u16* qb     = (u16*)(ws + 16777216);   // [B,H,N,D]
    u16* kb     = (u16*)(ws + 25165824);   // [B,H,N,D]
    u16* vtb    = (u16*)(ws + 33554432);   // [B,H,D,N] (token-permuted /16)
    u16* ob     = (u16*)(ws + 41943040);   // [B,N,E] final attention output

    prep_kernel<<<dim3(3072), 256, 0, stream>>>(x, xb, Wqkv, wqkvT, Wproj, wprojT);
    gemm_qkv<<<dim3(24, 64), 256, 0, stream>>>(xb, wqkvT, bqkv, qb, kb, vtb);
    attn_kernel<<<dim3(512), 512, 0, stream>>>(qb, kb, vtb, ob);
    gemm_proj<<<dim3(1024), 256, 0, stream>>>(ob, wprojT, bproj, out);
}